// Round 2
// baseline (1235.585 us; speedup 1.0000x reference)
//
#include <hip/hip_runtime.h>
#include <stdint.h>

typedef uint32_t u32;
typedef unsigned long long u64;

#define NB 8
#define NPER 4000
#define NROWS (NB * NPER)
#define NC 91
#define NCLS 90
#define CAPMAX 76800   // hard bound: <=19 classes/proposal can have softmax > 0.05
#define NDET 100
#define KMAX 4096      // per-(image,class) segment cap; n <= NPER = 4000 always
#define SURVCAP 9216   // survivors per image cap (90 classes x 100 max = 9000)
#define TOPL 4096      // merge kernel LDS key pool

// ---------------------------------------------------------------- decode ----
__device__ __forceinline__ float4 decode_clip(float4 rel, float w, float h,
                                              float cx, float cy, float W, float H) {
  const float XCLIP = 4.135166556742356f;  // log(1000/16)
  float dx = rel.x / 10.0f;
  float dy = rel.y / 10.0f;
  float dw = fminf(rel.z / 5.0f, XCLIP);
  float dh = fminf(rel.w / 5.0f, XCLIP);
  float qcx = dx * w + cx;
  float qcy = dy * h + cy;
  float qw = expf(dw) * w;
  float qh = expf(dh) * h;
  float x1 = qcx - 0.5f * qw, y1 = qcy - 0.5f * qh;
  float x2 = qcx + 0.5f * qw, y2 = qcy + 0.5f * qh;
  x1 = fminf(fmaxf(x1, 0.0f), W);
  x2 = fminf(fmaxf(x2, 0.0f), W);
  y1 = fminf(fmaxf(y1, 0.0f), H);
  y2 = fminf(fmaxf(y2, 0.0f), H);
  return make_float4(x1, y1, x2, y2);
}

// One wave (64 lanes) per proposal row. Lane handles class cA=lane and
// cB=64+lane (lane<27). Softmax over all 91 classes (incl. background).
__device__ __forceinline__ void row_candidates(const float* __restrict__ logits,
    const float* __restrict__ boxreg, const float* __restrict__ props,
    int r, int lane, float W, float H,
    int& cA, bool& vA, float& sA, float4& bA,
    int& cB, bool& vB, float& sB, float4& bB) {
  const float* lrow = logits + (size_t)r * NC;
  float xA = lrow[lane];
  float xB = (lane < NC - 64) ? lrow[64 + lane] : -3.0e38f;
  float mx = fmaxf(xA, xB);
  for (int o = 32; o; o >>= 1) mx = fmaxf(mx, __shfl_xor(mx, o));
  float eA = expf(xA - mx);
  float eB = (lane < NC - 64) ? expf(xB - mx) : 0.0f;
  float sm = eA + eB;
  for (int o = 32; o; o >>= 1) sm += __shfl_xor(sm, o);
  sA = eA / sm;
  sB = eB / sm;
  cA = lane;
  cB = 64 + lane;
  const float4 p = reinterpret_cast<const float4*>(props)[r];
  float w = p.z - p.x, h = p.w - p.y;
  float cx = p.x + 0.5f * w, cy = p.y + 0.5f * h;
  vA = (cA >= 1) && (sA > 0.05f);
  vB = (cB < NC) && (sB > 0.05f);
  bA = make_float4(0.f, 0.f, 0.f, 0.f);
  bB = bA;
  const float4* relrow = reinterpret_cast<const float4*>(boxreg) + (size_t)r * NC;
  if (vA) {
    bA = decode_clip(relrow[cA], w, h, cx, cy, W, H);
    vA = ((bA.z - bA.x) >= 0.01f) && ((bA.w - bA.y) >= 0.01f);
  }
  if (vB) {
    bB = decode_clip(relrow[cB], w, h, cx, cy, W, H);
    vB = ((bB.z - bB.x) >= 0.01f) && ((bB.w - bB.y) >= 0.01f);
  }
}

// ---------------------------------------------------------------- kernels ---
__global__ __launch_bounds__(1024) void k_zero(u32* ccount, u32* surv_cnt) {
  int t = threadIdx.x;
  if (t < NB * NCLS) ccount[t] = 0u;
  if (t < NB) surv_cnt[t] = 0u;
}

__global__ __launch_bounds__(256) void k_count(const float* __restrict__ logits,
    const float* __restrict__ boxreg, const float* __restrict__ props,
    const int* __restrict__ dh, const int* __restrict__ dw, u32* ccount) {
  int gt = blockIdx.x * 256 + threadIdx.x;
  int r = gt >> 6, lane = gt & 63;
  if (r >= NROWS) return;
  float H = (float)dh[0], W = (float)dw[0];
  int cA, cB; bool vA, vB; float sA, sB; float4 bA, bB;
  row_candidates(logits, boxreg, props, r, lane, W, H, cA, vA, sA, bA, cB, vB, sB, bB);
  int b = r / NPER;
  if (vA) atomicAdd(ccount + b * NCLS + (cA - 1), 1u);
  if (vB) atomicAdd(ccount + b * NCLS + (cB - 1), 1u);
}

// segmented (per-image) exclusive scan over the 8x90 class counts
__global__ __launch_bounds__(1024) void k_scan(const u32* __restrict__ ccount, u32* cbase) {
  __shared__ u32 s[NB * NCLS];
  int t = threadIdx.x;
  u32 own = 0;
  if (t < NB * NCLS) { own = ccount[t]; s[t] = own; }
  __syncthreads();
  int i = t % NCLS;
  for (int off = 1; off < NCLS; off <<= 1) {
    u32 add = 0;
    if (t < NB * NCLS && i >= off) add = s[t - off];
    __syncthreads();
    if (t < NB * NCLS) s[t] += add;
    __syncthreads();
  }
  if (t < NB * NCLS) cbase[t] = s[t] - own;  // exclusive; k_place restores inclusive
}

__global__ __launch_bounds__(256) void k_place(const float* __restrict__ logits,
    const float* __restrict__ boxreg, const float* __restrict__ props,
    const int* __restrict__ dh, const int* __restrict__ dw, u32* cbase,
    float4* box_all, u64* key_all, u32* pack_all, int CAP) {
  int gt = blockIdx.x * 256 + threadIdx.x;
  int r = gt >> 6, lane = gt & 63;
  if (r >= NROWS) return;
  float H = (float)dh[0], W = (float)dw[0];
  int cA, cB; bool vA, vB; float sA, sB; float4 bA, bB;
  row_candidates(logits, boxreg, props, r, lane, W, H, cA, vA, sA, bA, cB, vB, sB, bB);
  int b = r / NPER;
  int rl = r - b * NPER;
  size_t base = (size_t)b * CAP;
  if (vA) {
    u32 pos = atomicAdd(cbase + b * NCLS + (cA - 1), 1u);
    if (pos < (u32)CAP) {
      u32 orig = (u32)(rl * NCLS + (cA - 1));       // flat index in reference M ordering
      box_all[base + pos] = bA;
      key_all[base + pos] = ((u64)__float_as_uint(sA) << 22) | (u64)(0x3FFFFFu - orig);
      pack_all[base + pos] = orig | ((u32)cA << 22);
    }
  }
  if (vB) {
    u32 pos = atomicAdd(cbase + b * NCLS + (cB - 1), 1u);
    if (pos < (u32)CAP) {
      u32 orig = (u32)(rl * NCLS + (cB - 1));
      box_all[base + pos] = bB;
      key_all[base + pos] = ((u64)__float_as_uint(sB) << 22) | (u64)(0x3FFFFFu - orig);
      pack_all[base + pos] = orig | ((u32)cB << 22);
    }
  }
}

// Per-(image,class) greedy NMS. One 256-thread block per (b,c) pair.
// Bitonic-sorts the class segment by key (descending), then greedy with
// early exit at NDET survivors. Survivor slots appended to per-image list.
__global__ __launch_bounds__(256) void k_nms_class(const u32* __restrict__ cbase_post,
    const float4* __restrict__ box_all, const u64* __restrict__ key_all,
    u32* surv_cnt, u32* sslot,
    const int* __restrict__ dh, const int* __restrict__ dw, int CAP) {
  __shared__ u64 k[KMAX];
  __shared__ u32 id[KMAX];
  __shared__ u32 s_slots[NDET];
  __shared__ float4 s_A;
  __shared__ float s_aA;
  __shared__ u32 s_found, s_ns, s_base;

  int b = blockIdx.x / NCLS;
  int ci = blockIdx.x % NCLS;
  const u32* post = cbase_post + b * NCLS;  // inclusive class ends after k_place
  u32 s0 = (ci == 0) ? 0u : post[ci - 1];
  u32 s1 = post[ci];
  if (s0 > (u32)CAP) s0 = (u32)CAP;
  if (s1 > (u32)CAP) s1 = (u32)CAP;
  int n = (int)(s1 - s0);
  if (n <= 0) return;

  int tid = threadIdx.x;
  float H = (float)dh[0], W = (float)dw[0];
  float off_unit = fmaxf(H, W) + 1.0f;
  float loff = (float)(ci + 1) * off_unit;
  size_t segbase = (size_t)b * CAP + s0;

  int m = 1;
  while (m < n) m <<= 1;
  for (int j = tid; j < m; j += 256) {
    k[j] = (j < n) ? key_all[segbase + j] : 0ull;
    id[j] = (u32)j;
  }
  if (tid == 0) s_ns = 0;
  __syncthreads();

  // bitonic sort descending on k (companion id)
  for (int len = 2; len <= m; len <<= 1) {
    for (int str = len >> 1; str > 0; str >>= 1) {
      for (int i = tid; i < (m >> 1); i += 256) {
        int a = 2 * str * (i / str) + (i % str);
        int bb = a + str;
        bool desc = ((a & len) == 0);
        u64 ka = k[a], kb = k[bb];
        bool sw = desc ? (ka < kb) : (ka > kb);
        if (sw) {
          k[a] = kb; k[bb] = ka;
          u32 tmp = id[a]; id[a] = id[bb]; id[bb] = tmp;
        }
      }
      __syncthreads();
    }
  }

  // greedy: sorted descending, all real keys in [0, n)
  u32 cur = 0;
  while (true) {
    if (tid == 0) s_found = 0xFFFFFFFFu;
    __syncthreads();
    for (u32 j = cur + tid; j < (u32)n; j += 256) {
      if (k[j]) { atomicMin(&s_found, j); break; }  // strided asc: first hit is this thread's min
    }
    __syncthreads();
    u32 f = s_found;
    if (f == 0xFFFFFFFFu) break;
    if (tid == 0) {
      u32 slot = (u32)(segbase + id[f]);
      float4 bx = box_all[slot];
      float4 ob = make_float4(bx.x + loff, bx.y + loff, bx.z + loff, bx.w + loff);
      s_A = ob;
      s_aA = (ob.z - ob.x) * (ob.w - ob.y);
      s_slots[s_ns] = slot;
      s_ns = s_ns + 1;
      k[f] = 0ull;
    }
    __syncthreads();
    float4 A = s_A;
    float aA = s_aA;
    for (u32 j = f + 1 + tid; j < (u32)n; j += 256) {
      if (!k[j]) continue;
      float4 bj = box_all[segbase + id[j]];
      float4 Bb = make_float4(bj.x + loff, bj.y + loff, bj.z + loff, bj.w + loff);
      float ix1 = fmaxf(A.x, Bb.x), iy1 = fmaxf(A.y, Bb.y);
      float ix2 = fminf(A.z, Bb.z), iy2 = fminf(A.w, Bb.w);
      float inter = fmaxf(ix2 - ix1, 0.0f) * fmaxf(iy2 - iy1, 0.0f);
      float aB = (Bb.z - Bb.x) * (Bb.w - Bb.y);
      float iou = inter / fmaxf(aA + aB - inter, 1e-9f);
      if (iou > 0.5f) k[j] = 0ull;
    }
    __syncthreads();
    cur = f + 1;
    if (s_ns >= NDET) break;
  }
  __syncthreads();
  u32 ns = s_ns;
  if (ns == 0) return;
  if (tid == 0) s_base = atomicAdd(surv_cnt + b, ns);
  __syncthreads();
  u32 base = s_base;
  for (u32 i = tid; i < ns; i += 256) {
    u32 p = base + i;
    if (p < SURVCAP) sslot[(size_t)b * SURVCAP + p] = s_slots[i];
  }
}

// Per-image top-NDET merge over class-NMS survivors, in exact reference
// selection order (key = score, then smallest flat index).
__global__ __launch_bounds__(256) void k_top(const u32* __restrict__ surv_cnt,
    const u32* __restrict__ sslot, const float4* __restrict__ box_all,
    u64* key_all, const u32* __restrict__ pack_all, float* out) {
  __shared__ u64 kk[TOPL];
  __shared__ float s_out[NDET][8];
  __shared__ u64 s_rk[4];
  __shared__ int s_rj[4];
  __shared__ u32 s_done;

  int b = blockIdx.x;
  int tid = threadIdx.x;
  u32 ns = surv_cnt[b];
  if (ns > SURVCAP) ns = SURVCAP;
  int nl = (ns < TOPL) ? (int)ns : TOPL;
  const u32* sl = sslot + (size_t)b * SURVCAP;

  for (int j = tid; j < nl; j += 256) kk[j] = key_all[sl[j]];
  for (int j = tid; j < NDET * 8; j += 256) ((float*)s_out)[j] = 0.0f;
  if (tid == 0) s_done = 0;
  __syncthreads();

  for (int t = 0; t < NDET; ++t) {
    u64 bk = 0; int bj = -1;
    for (int j = tid; j < nl; j += 256) { u64 g = kk[j]; if (g > bk) { bk = g; bj = j; } }
    for (int j = TOPL + tid; j < (int)ns; j += 256) {
      u64 g = key_all[sl[j]];
      if (g > bk) { bk = g; bj = j; }
    }
    for (int o = 32; o; o >>= 1) {
      u64 ok_ = __shfl_xor(bk, o);
      int oj = __shfl_xor(bj, o);
      if (ok_ > bk) { bk = ok_; bj = oj; }
    }
    if ((tid & 63) == 0) { s_rk[tid >> 6] = bk; s_rj[tid >> 6] = bj; }
    __syncthreads();
    if (tid == 0) {
      for (int w = 1; w < 4; ++w) if (s_rk[w] > bk) { bk = s_rk[w]; bj = s_rj[w]; }
      if (bk == 0) {
        s_done = 1;
      } else {
        u32 slot = sl[bj];
        float4 bx = box_all[slot];
        u32 pack = pack_all[slot];
        float* o7 = s_out[t];
        o7[0] = bx.x; o7[1] = bx.y; o7[2] = bx.z; o7[3] = bx.w;
        o7[4] = __uint_as_float((u32)(bk >> 22));
        o7[5] = (float)(pack >> 22);
        o7[6] = 1.0f;
        if (bj < TOPL) kk[bj] = 0ull; else key_all[slot] = 0ull;
      }
    }
    __syncthreads();
    if (s_done) break;
  }
  __syncthreads();
  // boxes[3200] | scores[800] | labels[800] | keep[800]
  if (tid < NDET) {
    const float* o7 = s_out[tid];
    float* ob_out = out + ((size_t)b * NDET + tid) * 4;
    ob_out[0] = o7[0]; ob_out[1] = o7[1]; ob_out[2] = o7[2]; ob_out[3] = o7[3];
    out[NB * NDET * 4 + b * NDET + tid] = o7[4];
    out[NB * NDET * 5 + b * NDET + tid] = o7[5];
    out[NB * NDET * 6 + b * NDET + tid] = o7[6];
  }
}

// ---------------------------------------------------------------- launch ----
extern "C" void kernel_launch(void* const* d_in, const int* in_sizes, int n_in,
                              void* d_out, int out_size, void* d_ws, size_t ws_size,
                              hipStream_t stream) {
  const float* logits = (const float*)d_in[0];
  const float* boxreg = (const float*)d_in[1];
  const float* props  = (const float*)d_in[2];
  const int* dh = (const int*)d_in[3];
  const int* dw = (const int*)d_in[4];
  float* out = (float*)d_out;

  char* ws = (char*)d_ws;
  u32* ccount   = (u32*)ws;             // 720 u32
  u32* cbase    = (u32*)(ws + 4096);    // 720 u32
  u32* surv_cnt = (u32*)(ws + 8192);    // 8 u32
  u32* sslot    = (u32*)(ws + 12288);   // NB*SURVCAP u32 = 288 KB
  size_t reserve = 12288 + (size_t)NB * SURVCAP * 4;
  reserve = (reserve + 255) & ~(size_t)255;
  char* arrs = ws + reserve;
  size_t avail = (ws_size > reserve) ? (ws_size - reserve) : 0;
  size_t cap = avail / (NB * 28);       // 16B box + 8B key + 4B pack per candidate
  if (cap > CAPMAX) cap = CAPMAX;
  cap &= ~(size_t)15;
  int CAP = (int)cap;
  float4* box_all = (float4*)arrs;
  u64* key_all = (u64*)(box_all + (size_t)NB * CAP);
  u32* pack_all = (u32*)(key_all + (size_t)NB * CAP);

  k_zero<<<1, 1024, 0, stream>>>(ccount, surv_cnt);
  k_count<<<NROWS / 4, 256, 0, stream>>>(logits, boxreg, props, dh, dw, ccount);
  k_scan<<<1, 1024, 0, stream>>>(ccount, cbase);
  k_place<<<NROWS / 4, 256, 0, stream>>>(logits, boxreg, props, dh, dw, cbase,
                                         box_all, key_all, pack_all, CAP);
  k_nms_class<<<NB * NCLS, 256, 0, stream>>>(cbase, box_all, key_all,
                                             surv_cnt, sslot, dh, dw, CAP);
  k_top<<<NB, 256, 0, stream>>>(surv_cnt, sslot, box_all, key_all, pack_all, out);
}

// Round 3
// 462.994 us; speedup vs baseline: 2.6687x; 2.6687x over previous
//
#include <hip/hip_runtime.h>
#include <stdint.h>

typedef uint32_t u32;
typedef unsigned long long u64;

#define NB 8
#define NPER 4000
#define NROWS (NB * NPER)
#define NC 91
#define NCLS 90
#define CAPMAX 76800   // hard bound: <=19 classes/proposal can have softmax > 0.05
#define NDET 100
#define KMAX 4096      // per-(image,class) segment cap; n <= NPER = 4000 always
#define SURVCAP 9216   // survivors per image cap (90 classes x 100 max = 9000)
#define FKCAP 1024     // k_top final candidate pool (>=100 + ties)

// ---------------------------------------------------------------- decode ----
__device__ __forceinline__ float4 decode_clip(float4 rel, float w, float h,
                                              float cx, float cy, float W, float H) {
  const float XCLIP = 4.135166556742356f;  // log(1000/16)
  float dx = rel.x / 10.0f;
  float dy = rel.y / 10.0f;
  float dw = fminf(rel.z / 5.0f, XCLIP);
  float dh = fminf(rel.w / 5.0f, XCLIP);
  float qcx = dx * w + cx;
  float qcy = dy * h + cy;
  float qw = expf(dw) * w;
  float qh = expf(dh) * h;
  float x1 = qcx - 0.5f * qw, y1 = qcy - 0.5f * qh;
  float x2 = qcx + 0.5f * qw, y2 = qcy + 0.5f * qh;
  x1 = fminf(fmaxf(x1, 0.0f), W);
  x2 = fminf(fmaxf(x2, 0.0f), W);
  y1 = fminf(fmaxf(y1, 0.0f), H);
  y2 = fminf(fmaxf(y2, 0.0f), H);
  return make_float4(x1, y1, x2, y2);
}

// One wave (64 lanes) per proposal row. Lane handles class cA=lane and
// cB=64+lane (lane<27). Softmax over all 91 classes (incl. background).
__device__ __forceinline__ void row_candidates(const float* __restrict__ logits,
    const float* __restrict__ boxreg, const float* __restrict__ props,
    int r, int lane, float W, float H,
    int& cA, bool& vA, float& sA, float4& bA,
    int& cB, bool& vB, float& sB, float4& bB) {
  const float* lrow = logits + (size_t)r * NC;
  float xA = lrow[lane];
  float xB = (lane < NC - 64) ? lrow[64 + lane] : -3.0e38f;
  float mx = fmaxf(xA, xB);
  for (int o = 32; o; o >>= 1) mx = fmaxf(mx, __shfl_xor(mx, o));
  float eA = expf(xA - mx);
  float eB = (lane < NC - 64) ? expf(xB - mx) : 0.0f;
  float sm = eA + eB;
  for (int o = 32; o; o >>= 1) sm += __shfl_xor(sm, o);
  sA = eA / sm;
  sB = eB / sm;
  cA = lane;
  cB = 64 + lane;
  const float4 p = reinterpret_cast<const float4*>(props)[r];
  float w = p.z - p.x, h = p.w - p.y;
  float cx = p.x + 0.5f * w, cy = p.y + 0.5f * h;
  vA = (cA >= 1) && (sA > 0.05f);
  vB = (cB < NC) && (sB > 0.05f);
  bA = make_float4(0.f, 0.f, 0.f, 0.f);
  bB = bA;
  const float4* relrow = reinterpret_cast<const float4*>(boxreg) + (size_t)r * NC;
  if (vA) {
    bA = decode_clip(relrow[cA], w, h, cx, cy, W, H);
    vA = ((bA.z - bA.x) >= 0.01f) && ((bA.w - bA.y) >= 0.01f);
  }
  if (vB) {
    bB = decode_clip(relrow[cB], w, h, cx, cy, W, H);
    vB = ((bB.z - bB.x) >= 0.01f) && ((bB.w - bB.y) >= 0.01f);
  }
}

// ---------------------------------------------------------------- kernels ---
__global__ __launch_bounds__(1024) void k_zero(u32* ccount, u32* surv_cnt) {
  int t = threadIdx.x;
  if (t < NB * NCLS) ccount[t] = 0u;
  if (t < NB) surv_cnt[t] = 0u;
}

__global__ __launch_bounds__(256) void k_count(const float* __restrict__ logits,
    const float* __restrict__ boxreg, const float* __restrict__ props,
    const int* __restrict__ dh, const int* __restrict__ dw, u32* ccount) {
  int gt = blockIdx.x * 256 + threadIdx.x;
  int r = gt >> 6, lane = gt & 63;
  if (r >= NROWS) return;
  float H = (float)dh[0], W = (float)dw[0];
  int cA, cB; bool vA, vB; float sA, sB; float4 bA, bB;
  row_candidates(logits, boxreg, props, r, lane, W, H, cA, vA, sA, bA, cB, vB, sB, bB);
  int b = r / NPER;
  if (vA) atomicAdd(ccount + b * NCLS + (cA - 1), 1u);
  if (vB) atomicAdd(ccount + b * NCLS + (cB - 1), 1u);
}

// segmented (per-image) exclusive scan over the 8x90 class counts
__global__ __launch_bounds__(1024) void k_scan(const u32* __restrict__ ccount, u32* cbase) {
  __shared__ u32 s[NB * NCLS];
  int t = threadIdx.x;
  u32 own = 0;
  if (t < NB * NCLS) { own = ccount[t]; s[t] = own; }
  __syncthreads();
  int i = t % NCLS;
  for (int off = 1; off < NCLS; off <<= 1) {
    u32 add = 0;
    if (t < NB * NCLS && i >= off) add = s[t - off];
    __syncthreads();
    if (t < NB * NCLS) s[t] += add;
    __syncthreads();
  }
  if (t < NB * NCLS) cbase[t] = s[t] - own;  // exclusive; k_place restores inclusive
}

__global__ __launch_bounds__(256) void k_place(const float* __restrict__ logits,
    const float* __restrict__ boxreg, const float* __restrict__ props,
    const int* __restrict__ dh, const int* __restrict__ dw, u32* cbase,
    float4* box_all, u64* key_all, int CAP) {
  int gt = blockIdx.x * 256 + threadIdx.x;
  int r = gt >> 6, lane = gt & 63;
  if (r >= NROWS) return;
  float H = (float)dh[0], W = (float)dw[0];
  int cA, cB; bool vA, vB; float sA, sB; float4 bA, bB;
  row_candidates(logits, boxreg, props, r, lane, W, H, cA, vA, sA, bA, cB, vB, sB, bB);
  int b = r / NPER;
  int rl = r - b * NPER;
  size_t base = (size_t)b * CAP;
  if (vA) {
    u32 pos = atomicAdd(cbase + b * NCLS + (cA - 1), 1u);
    if (pos < (u32)CAP) {
      u32 orig = (u32)(rl * NCLS + (cA - 1));  // flat index in reference M ordering
      box_all[base + pos] = bA;
      key_all[base + pos] = ((u64)__float_as_uint(sA) << 22) | (u64)(0x3FFFFFu - orig);
    }
  }
  if (vB) {
    u32 pos = atomicAdd(cbase + b * NCLS + (cB - 1), 1u);
    if (pos < (u32)CAP) {
      u32 orig = (u32)(rl * NCLS + (cB - 1));
      box_all[base + pos] = bB;
      key_all[base + pos] = ((u64)__float_as_uint(sB) << 22) | (u64)(0x3FFFFFu - orig);
    }
  }
}

// Per-(image,class) greedy NMS: ONE WAVE per (b,c). Bitonic sort of the
// segment (desc by key), then ballot-based wave NMS: 64 boxes/chunk in
// registers, suppress vs prior survivors (LDS broadcast), then serial
// intra-chunk selection via ballot/ctz/shfl. Early exit at NDET survivors.
__global__ __launch_bounds__(64) void k_nms_class(const u32* __restrict__ cbase_post,
    const float4* __restrict__ box_all, const u64* __restrict__ key_all,
    u32* surv_cnt, u32* sslot, u64* skey_out,
    const int* __restrict__ dh, const int* __restrict__ dw, int CAP) {
  __shared__ u64 k[KMAX];
  __shared__ u32 id[KMAX];
  __shared__ float4 s_sb[NDET];
  __shared__ float s_sa[NDET];
  __shared__ u64 s_sk[NDET];
  __shared__ u32 s_ss[NDET];

  int b = blockIdx.x / NCLS;
  int ci = blockIdx.x % NCLS;
  const u32* post = cbase_post + b * NCLS;  // inclusive class ends after k_place
  u32 s0 = ci ? post[ci - 1] : 0u;
  u32 s1 = post[ci];
  if (s0 > (u32)CAP) s0 = (u32)CAP;
  if (s1 > (u32)CAP) s1 = (u32)CAP;
  int n = (int)(s1 - s0);
  if (n <= 0) return;

  int lane = threadIdx.x;
  float H = (float)dh[0], W = (float)dw[0];
  float loff = (fmaxf(H, W) + 1.0f) * (float)(ci + 1);
  size_t segbase = (size_t)b * CAP + s0;

  int m = 1;
  while (m < n) m <<= 1;
  for (int j = lane; j < m; j += 64) {
    k[j] = (j < n) ? key_all[segbase + j] : 0ull;
    id[j] = (u32)j;
  }
  __syncthreads();
  for (int len = 2; len <= m; len <<= 1) {
    for (int str = len >> 1; str > 0; str >>= 1) {
      for (int i = lane; i < (m >> 1); i += 64) {
        int a = 2 * str * (i / str) + (i % str);
        int c = a + str;
        bool desc = ((a & len) == 0);
        u64 ka = k[a], kc = k[c];
        if (desc ? (ka < kc) : (ka > kc)) {
          k[a] = kc; k[c] = ka;
          u32 t = id[a]; id[a] = id[c]; id[c] = t;
        }
      }
      __syncthreads();  // single wave: compiles to waitcnt, no real barrier
    }
  }

  int S = 0;
  for (int base = 0; base < n && S < NDET; base += 64) {
    int i = base + lane;
    bool have = (i < n);
    float4 Bb = make_float4(0.f, 0.f, 0.f, 0.f);
    float aB = 0.f;
    u64 mykey = 0ull;
    u32 myslot = 0;
    if (have) {
      myslot = (u32)(segbase + id[i]);
      float4 bx = box_all[myslot];
      Bb = make_float4(bx.x + loff, bx.y + loff, bx.z + loff, bx.w + loff);
      aB = (Bb.z - Bb.x) * (Bb.w - Bb.y);
      mykey = k[i];
    }
    bool alive = have;
    // suppression by survivors from earlier chunks (broadcast LDS reads)
    for (int s = 0; s < S; ++s) {
      float4 A = s_sb[s];
      float aA = s_sa[s];
      float ix1 = fmaxf(A.x, Bb.x), iy1 = fmaxf(A.y, Bb.y);
      float ix2 = fminf(A.z, Bb.z), iy2 = fminf(A.w, Bb.w);
      float inter = fmaxf(ix2 - ix1, 0.0f) * fmaxf(iy2 - iy1, 0.0f);
      float iou = inter / fmaxf(aA + aB - inter, 1e-9f);
      if (alive && iou > 0.5f) alive = false;
    }
    u64 mask = __ballot(alive);
    while (mask && S < NDET) {
      int j = __builtin_ctzll(mask);
      float Ax = __shfl(Bb.x, j), Ay = __shfl(Bb.y, j);
      float Az = __shfl(Bb.z, j), Aw = __shfl(Bb.w, j);
      float aA = __shfl(aB, j);
      if (lane == j) {
        s_sb[S] = Bb; s_sa[S] = aB; s_sk[S] = mykey; s_ss[S] = myslot;
      }
      float ix1 = fmaxf(Ax, Bb.x), iy1 = fmaxf(Ay, Bb.y);
      float ix2 = fminf(Az, Bb.z), iy2 = fminf(Aw, Bb.w);
      float inter = fmaxf(ix2 - ix1, 0.0f) * fmaxf(iy2 - iy1, 0.0f);
      float iou = inter / fmaxf(aA + aB - inter, 1e-9f);
      if (alive && iou > 0.5f) alive = false;  // selected lane: IoU=1 -> leaves mask
      ++S;
      mask = __ballot(alive);
    }
    __syncthreads();
  }
  if (S == 0) return;
  int basep = 0;
  if (lane == 0) basep = (int)atomicAdd(surv_cnt + b, (u32)S);
  basep = __shfl(basep, 0);
  for (int i2 = lane; i2 < S; i2 += 64) {
    u32 p = (u32)(basep + i2);
    if (p < SURVCAP) {
      sslot[(size_t)b * SURVCAP + p] = s_ss[i2];
      skey_out[(size_t)b * SURVCAP + p] = s_sk[i2];
    }
  }
}

// Per-image exact top-NDET: 4-pass radix select on score bits finds the
// 100th-largest score T; compact >T plus ==T ties; one bitonic sort by full
// key (score, then smallest flat index) = exact reference selection order.
__global__ __launch_bounds__(256) void k_top(const u32* __restrict__ surv_cnt,
    const u32* __restrict__ sslot, const u64* __restrict__ skey,
    const float4* __restrict__ box_all, float* out) {
  __shared__ u32 ssc[SURVCAP];
  __shared__ u32 hist[256];
  __shared__ u32 s_sel[3];   // prefix, pmask, need
  __shared__ u32 s_cnt[2];   // compaction counters
  __shared__ u64 fk[FKCAP];
  __shared__ u32 fs[FKCAP];

  int b = blockIdx.x;
  int tid = threadIdx.x;
  u32 ns = surv_cnt[b];
  if (ns > SURVCAP) ns = SURVCAP;
  const u64* kb = skey + (size_t)b * SURVCAP;
  const u32* sb = sslot + (size_t)b * SURVCAP;

  for (u32 j = tid; j < ns; j += 256) ssc[j] = (u32)(kb[j] >> 22);
  if (tid == 0) { s_cnt[0] = 0; s_cnt[1] = 0; }
  __syncthreads();

  u32 T = 0, need = 0;
  if (ns > NDET) {
    u32 prefix = 0, pmask = 0;
    need = NDET;
    for (int shift = 24; shift >= 0; shift -= 8) {
      hist[tid] = 0;
      __syncthreads();
      for (u32 j = tid; j < ns; j += 256) {
        u32 s = ssc[j];
        if ((s & pmask) == prefix) atomicAdd(&hist[(s >> shift) & 255u], 1u);
      }
      __syncthreads();
      if (tid == 0) {
        u32 acc = 0;
        int d = 255;
        for (; d > 0; --d) {
          u32 c = hist[d];
          if (acc + c >= need) break;
          acc += c;
        }
        s_sel[0] = prefix | ((u32)d << shift);
        s_sel[1] = pmask | (0xFFu << shift);
        s_sel[2] = need - acc;
      }
      __syncthreads();
      prefix = s_sel[0]; pmask = s_sel[1]; need = s_sel[2];
    }
    T = prefix;
  }
  __syncthreads();

  // compact: all (if ns<=NDET) or score>T
  for (u32 j = tid; j < ns; j += 256) {
    u32 s = ssc[j];
    bool take = (ns <= NDET) || (s > T);
    if (take) {
      u32 p = atomicAdd(&s_cnt[0], 1u);
      if (p < FKCAP) { fk[p] = kb[j]; fs[p] = sb[j]; }
    }
  }
  __syncthreads();
  if (tid == 0) s_cnt[1] = s_cnt[0];
  __syncthreads();
  if (ns > NDET) {  // append ==T ties; tie order resolved by full-key sort below
    for (u32 j = tid; j < ns; j += 256) {
      if (ssc[j] == T) {
        u32 p = atomicAdd(&s_cnt[1], 1u);
        if (p < FKCAP) { fk[p] = kb[j]; fs[p] = sb[j]; }
      }
    }
  }
  __syncthreads();
  u32 tot = s_cnt[1];
  if (tot > FKCAP) tot = FKCAP;
  u32 m2 = 1;
  while (m2 < tot) m2 <<= 1;
  if (m2 < 2) m2 = 2;
  for (u32 j = tot + tid; j < m2; j += 256) { fk[j] = 0ull; fs[j] = 0u; }
  __syncthreads();
  for (u32 len = 2; len <= m2; len <<= 1) {
    for (u32 str = len >> 1; str; str >>= 1) {
      for (u32 i = tid; i < (m2 >> 1); i += 256) {
        u32 a = 2 * str * (i / str) + (i % str);
        u32 c = a + str;
        bool desc = ((a & len) == 0);
        u64 ka = fk[a], kc = fk[c];
        if (desc ? (ka < kc) : (ka > kc)) {
          fk[a] = kc; fk[c] = ka;
          u32 t2 = fs[a]; fs[a] = fs[c]; fs[c] = t2;
        }
      }
      __syncthreads();
    }
  }
  // epilogue: boxes[3200] | scores[800] | labels[800] | keep[800]
  if (tid < NDET) {
    u64 key = ((u32)tid < tot) ? fk[tid] : 0ull;
    float b0 = 0.f, b1 = 0.f, b2 = 0.f, b3 = 0.f, sc = 0.f, lb = 0.f, kp = 0.f;
    if (key) {
      float4 bx = box_all[fs[tid]];
      b0 = bx.x; b1 = bx.y; b2 = bx.z; b3 = bx.w;
      sc = __uint_as_float((u32)(key >> 22));
      u32 orig = 0x3FFFFFu - (u32)(key & 0x3FFFFFu);
      lb = (float)(orig % NCLS + 1u);
      kp = 1.0f;
    }
    float* ob = out + ((size_t)b * NDET + tid) * 4;
    ob[0] = b0; ob[1] = b1; ob[2] = b2; ob[3] = b3;
    out[NB * NDET * 4 + b * NDET + tid] = sc;
    out[NB * NDET * 5 + b * NDET + tid] = lb;
    out[NB * NDET * 6 + b * NDET + tid] = kp;
  }
}

// ---------------------------------------------------------------- launch ----
extern "C" void kernel_launch(void* const* d_in, const int* in_sizes, int n_in,
                              void* d_out, int out_size, void* d_ws, size_t ws_size,
                              hipStream_t stream) {
  const float* logits = (const float*)d_in[0];
  const float* boxreg = (const float*)d_in[1];
  const float* props  = (const float*)d_in[2];
  const int* dh = (const int*)d_in[3];
  const int* dw = (const int*)d_in[4];
  float* out = (float*)d_out;

  char* ws = (char*)d_ws;
  u32* ccount   = (u32*)ws;             // 720 u32
  u32* cbase    = (u32*)(ws + 4096);    // 720 u32
  u32* surv_cnt = (u32*)(ws + 8192);    // 8 u32
  u32* sslot    = (u32*)(ws + 12288);   // NB*SURVCAP u32 = 288 KB
  u64* skey     = (u64*)(ws + 12288 + (size_t)NB * SURVCAP * 4);  // 576 KB
  size_t reserve = 12288 + (size_t)NB * SURVCAP * 12;
  reserve = (reserve + 255) & ~(size_t)255;
  char* arrs = ws + reserve;
  size_t avail = (ws_size > reserve) ? (ws_size - reserve) : 0;
  size_t cap = avail / (NB * 24);       // 16B box + 8B key per candidate
  if (cap > CAPMAX) cap = CAPMAX;
  cap &= ~(size_t)15;
  int CAP = (int)cap;
  float4* box_all = (float4*)arrs;
  u64* key_all = (u64*)(box_all + (size_t)NB * CAP);

  k_zero<<<1, 1024, 0, stream>>>(ccount, surv_cnt);
  k_count<<<NROWS / 4, 256, 0, stream>>>(logits, boxreg, props, dh, dw, ccount);
  k_scan<<<1, 1024, 0, stream>>>(ccount, cbase);
  k_place<<<NROWS / 4, 256, 0, stream>>>(logits, boxreg, props, dh, dw, cbase,
                                         box_all, key_all, CAP);
  k_nms_class<<<NB * NCLS, 64, 0, stream>>>(cbase, box_all, key_all,
                                            surv_cnt, sslot, skey, dh, dw, CAP);
  k_top<<<NB, 256, 0, stream>>>(surv_cnt, sslot, skey, box_all, out);
}

// Round 4
// 239.866 us; speedup vs baseline: 5.1511x; 1.9302x over previous
//
#include <hip/hip_runtime.h>
#include <stdint.h>

typedef uint32_t u32;
typedef unsigned long long u64;

#define NB 8
#define NPER 4000
#define NC 91
#define NCLS 90
#define NDET 100
#define CHUNKS 32
#define RPB 125        // rows per k_score block = NPER/CHUNKS
#define LBIN 32        // LDS bin capacity per class per block
#define BINCAP 512     // global bin capacity per (image,class); avg ~180
#define CSTRIDE 16     // u32 stride: one counter per 64B line (atomic serialization)
#define SURVCAP 9216   // >= 90*100
#define FKCAP 1024     // k_top final pool (100 + score ties)

// ---------------------------------------------------------------- decode ----
// bit-identical to reference op order (verified absmax 0.0 in R1-R3)
__device__ __forceinline__ float4 decode_clip(float4 rel, float w, float h,
                                              float cx, float cy, float W, float H) {
  const float XCLIP = 4.135166556742356f;  // log(1000/16)
  float dx = rel.x / 10.0f;
  float dy = rel.y / 10.0f;
  float dw = fminf(rel.z / 5.0f, XCLIP);
  float dh = fminf(rel.w / 5.0f, XCLIP);
  float qcx = dx * w + cx;
  float qcy = dy * h + cy;
  float qw = expf(dw) * w;
  float qh = expf(dh) * h;
  float x1 = qcx - 0.5f * qw, y1 = qcy - 0.5f * qh;
  float x2 = qcx + 0.5f * qw, y2 = qcy + 0.5f * qh;
  x1 = fminf(fmaxf(x1, 0.0f), W);
  x2 = fminf(fmaxf(x2, 0.0f), W);
  y1 = fminf(fmaxf(y1, 0.0f), H);
  y2 = fminf(fmaxf(y2, 0.0f), H);
  return make_float4(x1, y1, x2, y2);
}

// ---------------------------------------------------------------- kernels ---
__global__ __launch_bounds__(1024) void k_zero(u32* bin_cnt, u32* surv_cnt) {
  int t = threadIdx.x;
  for (int j = t; j < NB * NCLS * CSTRIDE; j += 1024) bin_cnt[j] = 0u;
  if (t < NB) surv_cnt[t] = 0u;
}

// Single front-end pass: softmax only (no decode). One wave per row; block
// covers 125 rows of one image. Candidates aggregated in LDS class bins,
// flushed with ONE global atomic per non-empty class per block.
__global__ __launch_bounds__(1024) void k_score(const float* __restrict__ logits,
    u32* bin_cnt, u64* bins) {
  __shared__ u64 s_key[NCLS][LBIN];
  __shared__ u32 s_cnt[NCLS];
  int tid = threadIdx.x;
  int b = blockIdx.x / CHUNKS;
  int chunk = blockIdx.x % CHUNKS;
  int wave = tid >> 6, lane = tid & 63;
  if (tid < NCLS) s_cnt[tid] = 0u;
  __syncthreads();

  for (int rloc = wave; rloc < RPB; rloc += 16) {
    int rl = chunk * RPB + rloc;
    int r = b * NPER + rl;
    const float* lrow = logits + (size_t)r * NC;
    float xA = lrow[lane];
    float xB = (lane < NC - 64) ? lrow[64 + lane] : -3.0e38f;
    float mx = fmaxf(xA, xB);
    for (int o = 32; o; o >>= 1) mx = fmaxf(mx, __shfl_xor(mx, o));
    float eA = expf(xA - mx);
    float eB = (lane < NC - 64) ? expf(xB - mx) : 0.0f;
    float sm = eA + eB;
    for (int o = 32; o; o >>= 1) sm += __shfl_xor(sm, o);
    float sA = eA / sm;
    float sB = eB / sm;
    if (lane >= 1 && sA > 0.05f) {          // class = lane
      int ci = lane - 1;
      u32 orig = (u32)(rl * NCLS + ci);
      u64 key = ((u64)__float_as_uint(sA) << 22) | (u64)(0x3FFFFFu - orig);
      u32 lp = atomicAdd(&s_cnt[ci], 1u);
      if (lp < LBIN) s_key[ci][lp] = key;
      else {  // rare overflow: direct global (slot disjointness via same counter)
        u32 gp = atomicAdd(&bin_cnt[(b * NCLS + ci) * CSTRIDE], 1u);
        if (gp < BINCAP) bins[((size_t)b * NCLS + ci) * BINCAP + gp] = key;
      }
    }
    if (lane < NC - 64 && sB > 0.05f) {     // class = 64 + lane
      int ci = 63 + lane;
      u32 orig = (u32)(rl * NCLS + ci);
      u64 key = ((u64)__float_as_uint(sB) << 22) | (u64)(0x3FFFFFu - orig);
      u32 lp = atomicAdd(&s_cnt[ci], 1u);
      if (lp < LBIN) s_key[ci][lp] = key;
      else {
        u32 gp = atomicAdd(&bin_cnt[(b * NCLS + ci) * CSTRIDE], 1u);
        if (gp < BINCAP) bins[((size_t)b * NCLS + ci) * BINCAP + gp] = key;
      }
    }
  }
  __syncthreads();
  if (tid < NCLS) {
    u32 cnt = s_cnt[tid];
    u32 cl = (cnt < LBIN) ? cnt : LBIN;
    if (cl) {
      u32 base = atomicAdd(&bin_cnt[(b * NCLS + tid) * CSTRIDE], cl);
      u64* dst = bins + ((size_t)b * NCLS + tid) * BINCAP;
      for (u32 j = 0; j < cl; ++j) {
        u32 p = base + j;
        if (p < BINCAP) dst[p] = s_key[tid][j];
      }
    }
  }
}

// Per-(image,class) greedy NMS: ONE WAVE per (b,c). Bitonic sort of bin keys
// (desc), lazy box decode per 64-chunk, ballot-based greedy. Candidates
// failing MIN_SIZE are carried dead (never selected, never suppress) ==
// reference's pre-filter. Early exit at NDET survivors.
__global__ __launch_bounds__(64) void k_nms_class(const u32* __restrict__ bin_cnt,
    const u64* __restrict__ bins, const float* __restrict__ boxreg,
    const float* __restrict__ props, u32* surv_cnt, u64* skey, float4* sbox,
    const int* __restrict__ dh, const int* __restrict__ dw) {
  __shared__ u64 k[BINCAP];
  __shared__ float4 s_sb[NDET];   // offset boxes (IoU space)
  __shared__ float s_sa[NDET];
  __shared__ float4 s_raw[NDET];  // raw boxes (output space)
  __shared__ u64 s_sk[NDET];

  int b = blockIdx.x / NCLS;
  int ci = blockIdx.x % NCLS;
  u32 cnt = bin_cnt[(b * NCLS + ci) * CSTRIDE];
  int n = (int)((cnt < BINCAP) ? cnt : BINCAP);
  if (n <= 0) return;

  int lane = threadIdx.x;
  float H = (float)dh[0], W = (float)dw[0];
  float loff = (fmaxf(H, W) + 1.0f) * (float)(ci + 1);
  const u64* bin = bins + ((size_t)b * NCLS + ci) * BINCAP;
  const float4* props4 = (const float4*)props;
  const float4* breg4 = (const float4*)boxreg;

  int m = 1;
  while (m < n) m <<= 1;
  if (m < 2) m = 2;
  for (int j = lane; j < m; j += 64) k[j] = (j < n) ? bin[j] : 0ull;
  __syncthreads();
  for (int len = 2; len <= m; len <<= 1) {
    for (int str = len >> 1; str; str >>= 1) {
      for (int i = lane; i < (m >> 1); i += 64) {
        int a = 2 * str * (i / str) + (i % str);
        int c = a + str;
        bool desc = ((a & len) == 0);
        u64 ka = k[a], kc = k[c];
        if (desc ? (ka < kc) : (ka > kc)) { k[a] = kc; k[c] = ka; }
      }
      __syncthreads();  // single wave: no real barrier
    }
  }

  int S = 0;
  for (int base = 0; base < n && S < NDET; base += 64) {
    int i = base + lane;
    bool have = (i < n);
    u64 mykey = have ? k[i] : 0ull;
    float4 raw = make_float4(0.f, 0.f, 0.f, 0.f);
    float4 Bb = raw;
    float aB = 0.f;
    bool alive = false;
    if (have) {
      u32 orig = 0x3FFFFFu - (u32)(mykey & 0x3FFFFFu);
      u32 rl = orig / NCLS;
      int r = b * NPER + (int)rl;
      float4 p = props4[r];
      float w = p.z - p.x, h = p.w - p.y;
      float cx = p.x + 0.5f * w, cy = p.y + 0.5f * h;
      float4 rel = breg4[(size_t)r * NC + (ci + 1)];
      raw = decode_clip(rel, w, h, cx, cy, W, H);
      alive = ((raw.z - raw.x) >= 0.01f) && ((raw.w - raw.y) >= 0.01f);
      Bb = make_float4(raw.x + loff, raw.y + loff, raw.z + loff, raw.w + loff);
      aB = (Bb.z - Bb.x) * (Bb.w - Bb.y);
    }
    // suppression by survivors from earlier chunks
    for (int s = 0; s < S; ++s) {
      float4 A = s_sb[s];
      float aA = s_sa[s];
      float ix1 = fmaxf(A.x, Bb.x), iy1 = fmaxf(A.y, Bb.y);
      float ix2 = fminf(A.z, Bb.z), iy2 = fminf(A.w, Bb.w);
      float inter = fmaxf(ix2 - ix1, 0.0f) * fmaxf(iy2 - iy1, 0.0f);
      float iou = inter / fmaxf(aA + aB - inter, 1e-9f);
      if (alive && iou > 0.5f) alive = false;
    }
    u64 mask = __ballot(alive);
    while (mask && S < NDET) {
      int j = __builtin_ctzll(mask);
      float Ax = __shfl(Bb.x, j), Ay = __shfl(Bb.y, j);
      float Az = __shfl(Bb.z, j), Aw = __shfl(Bb.w, j);
      float aA = __shfl(aB, j);
      if (lane == j) {
        s_sb[S] = Bb; s_sa[S] = aB; s_raw[S] = raw; s_sk[S] = mykey;
      }
      float ix1 = fmaxf(Ax, Bb.x), iy1 = fmaxf(Ay, Bb.y);
      float ix2 = fminf(Az, Bb.z), iy2 = fminf(Aw, Bb.w);
      float inter = fmaxf(ix2 - ix1, 0.0f) * fmaxf(iy2 - iy1, 0.0f);
      float iou = inter / fmaxf(aA + aB - inter, 1e-9f);
      if (alive && iou > 0.5f) alive = false;  // selected lane leaves via IoU=1
      ++S;
      mask = __ballot(alive);
    }
    __syncthreads();
  }
  if (S == 0) return;
  int basep = 0;
  if (lane == 0) basep = (int)atomicAdd(surv_cnt + b, (u32)S);
  basep = __shfl(basep, 0);
  for (int i2 = lane; i2 < S; i2 += 64) {
    u32 p = (u32)(basep + i2);
    if (p < SURVCAP) {
      skey[(size_t)b * SURVCAP + p] = s_sk[i2];
      sbox[(size_t)b * SURVCAP + p] = s_raw[i2];
    }
  }
}

// Per-image exact top-NDET: radix select on score bits -> threshold T,
// compact >T plus ==T ties, bitonic sort by full key = reference order.
__global__ __launch_bounds__(256) void k_top(const u32* __restrict__ surv_cnt,
    const u64* __restrict__ skey, const float4* __restrict__ sbox, float* out) {
  __shared__ u32 ssc[SURVCAP];
  __shared__ u32 hist[256];
  __shared__ u32 s_sel[3];
  __shared__ u32 s_cnt[2];
  __shared__ u64 fk[FKCAP];
  __shared__ u32 fs[FKCAP];

  int b = blockIdx.x;
  int tid = threadIdx.x;
  u32 ns = surv_cnt[b];
  if (ns > SURVCAP) ns = SURVCAP;
  const u64* kb = skey + (size_t)b * SURVCAP;

  for (u32 j = tid; j < ns; j += 256) ssc[j] = (u32)(kb[j] >> 22);
  if (tid == 0) { s_cnt[0] = 0; s_cnt[1] = 0; }
  __syncthreads();

  u32 T = 0;
  if (ns > NDET) {
    u32 prefix = 0, pmask = 0, need = NDET;
    for (int shift = 24; shift >= 0; shift -= 8) {
      hist[tid] = 0;
      __syncthreads();
      for (u32 j = tid; j < ns; j += 256) {
        u32 s = ssc[j];
        if ((s & pmask) == prefix) atomicAdd(&hist[(s >> shift) & 255u], 1u);
      }
      __syncthreads();
      if (tid == 0) {
        u32 acc = 0;
        int d = 255;
        for (; d > 0; --d) {
          u32 c = hist[d];
          if (acc + c >= need) break;
          acc += c;
        }
        s_sel[0] = prefix | ((u32)d << shift);
        s_sel[1] = pmask | (0xFFu << shift);
        s_sel[2] = need - acc;
      }
      __syncthreads();
      prefix = s_sel[0]; pmask = s_sel[1]; need = s_sel[2];
    }
    T = prefix;
  }
  __syncthreads();

  for (u32 j = tid; j < ns; j += 256) {
    bool take = (ns <= NDET) || (ssc[j] > T);
    if (take) {
      u32 p = atomicAdd(&s_cnt[0], 1u);
      if (p < FKCAP) { fk[p] = kb[j]; fs[p] = j; }
    }
  }
  __syncthreads();
  if (tid == 0) s_cnt[1] = s_cnt[0];
  __syncthreads();
  if (ns > NDET) {
    for (u32 j = tid; j < ns; j += 256) {
      if (ssc[j] == T) {
        u32 p = atomicAdd(&s_cnt[1], 1u);
        if (p < FKCAP) { fk[p] = kb[j]; fs[p] = j; }
      }
    }
  }
  __syncthreads();
  u32 tot = s_cnt[1];
  if (tot > FKCAP) tot = FKCAP;
  u32 m2 = 1;
  while (m2 < tot) m2 <<= 1;
  if (m2 < 2) m2 = 2;
  for (u32 j = tot + tid; j < m2; j += 256) { fk[j] = 0ull; fs[j] = 0u; }
  __syncthreads();
  for (u32 len = 2; len <= m2; len <<= 1) {
    for (u32 str = len >> 1; str; str >>= 1) {
      for (u32 i = tid; i < (m2 >> 1); i += 256) {
        u32 a = 2 * str * (i / str) + (i % str);
        u32 c = a + str;
        bool desc = ((a & len) == 0);
        u64 ka = fk[a], kc = fk[c];
        if (desc ? (ka < kc) : (ka > kc)) {
          fk[a] = kc; fk[c] = ka;
          u32 t2 = fs[a]; fs[a] = fs[c]; fs[c] = t2;
        }
      }
      __syncthreads();
    }
  }
  // boxes[3200] | scores[800] | labels[800] | keep[800]
  if (tid < NDET) {
    u64 key = ((u32)tid < tot) ? fk[tid] : 0ull;
    float b0 = 0.f, b1 = 0.f, b2 = 0.f, b3 = 0.f, sc = 0.f, lb = 0.f, kp = 0.f;
    if (key) {
      float4 bx = sbox[(size_t)b * SURVCAP + fs[tid]];
      b0 = bx.x; b1 = bx.y; b2 = bx.z; b3 = bx.w;
      sc = __uint_as_float((u32)(key >> 22));
      u32 orig = 0x3FFFFFu - (u32)(key & 0x3FFFFFu);
      lb = (float)(orig % NCLS + 1u);
      kp = 1.0f;
    }
    float* ob = out + ((size_t)b * NDET + tid) * 4;
    ob[0] = b0; ob[1] = b1; ob[2] = b2; ob[3] = b3;
    out[NB * NDET * 4 + b * NDET + tid] = sc;
    out[NB * NDET * 5 + b * NDET + tid] = lb;
    out[NB * NDET * 6 + b * NDET + tid] = kp;
  }
}

// ---------------------------------------------------------------- launch ----
extern "C" void kernel_launch(void* const* d_in, const int* in_sizes, int n_in,
                              void* d_out, int out_size, void* d_ws, size_t ws_size,
                              hipStream_t stream) {
  const float* logits = (const float*)d_in[0];
  const float* boxreg = (const float*)d_in[1];
  const float* props  = (const float*)d_in[2];
  const int* dh = (const int*)d_in[3];
  const int* dw = (const int*)d_in[4];
  float* out = (float*)d_out;

  char* ws = (char*)d_ws;
  u32* bin_cnt  = (u32*)ws;                                   // 720*16 u32 = 45 KiB
  u32* surv_cnt = (u32*)(ws + 46080);                         // 8 u32
  u64* bins     = (u64*)(ws + 46336);                         // 720*512*8 = 2.95 MB
  char* p2 = ws + 46336 + (size_t)NB * NCLS * BINCAP * 8;
  u64* skey = (u64*)p2;                                       // 8*9216*8 = 590 KB
  float4* sbox = (float4*)(p2 + (size_t)NB * SURVCAP * 8);    // 8*9216*16 = 1.18 MB
  (void)ws_size;

  k_zero<<<1, 1024, 0, stream>>>(bin_cnt, surv_cnt);
  k_score<<<NB * CHUNKS, 1024, 0, stream>>>(logits, bin_cnt, bins);
  k_nms_class<<<NB * NCLS, 64, 0, stream>>>(bin_cnt, bins, boxreg, props,
                                            surv_cnt, skey, sbox, dh, dw);
  k_top<<<NB, 256, 0, stream>>>(surv_cnt, skey, sbox, out);
}

// Round 5
// 211.118 us; speedup vs baseline: 5.8526x; 1.1362x over previous
//
#include <hip/hip_runtime.h>
#include <stdint.h>

typedef uint32_t u32;
typedef unsigned long long u64;

#define NB 8
#define NPER 4000
#define NC 91
#define NCLS 90
#define NDET 100
#define CHUNKS 32
#define RPB 125        // rows per k_score block = NPER/CHUNKS
#define LBIN 32        // LDS bin capacity per class per block
#define BINCAP 512     // global bin capacity per (image,class); avg ~180
#define CSTRIDE 16     // u32 stride: one counter per 64B line (atomic serialization)
#define SURVCAP 9216   // >= 90*100
#define FKCAP 1024     // k_top final pool (100 + score ties)

// ---------------------------------------------------------------- decode ----
// bit-identical to reference op order (verified absmax 0.0 in R1-R4)
__device__ __forceinline__ float4 decode_clip(float4 rel, float w, float h,
                                              float cx, float cy, float W, float H) {
  const float XCLIP = 4.135166556742356f;  // log(1000/16)
  float dx = rel.x / 10.0f;
  float dy = rel.y / 10.0f;
  float dw = fminf(rel.z / 5.0f, XCLIP);
  float dh = fminf(rel.w / 5.0f, XCLIP);
  float qcx = dx * w + cx;
  float qcy = dy * h + cy;
  float qw = expf(dw) * w;
  float qh = expf(dh) * h;
  float x1 = qcx - 0.5f * qw, y1 = qcy - 0.5f * qh;
  float x2 = qcx + 0.5f * qw, y2 = qcy + 0.5f * qh;
  x1 = fminf(fmaxf(x1, 0.0f), W);
  x2 = fminf(fmaxf(x2, 0.0f), W);
  y1 = fminf(fmaxf(y1, 0.0f), H);
  y2 = fminf(fmaxf(y2, 0.0f), H);
  return make_float4(x1, y1, x2, y2);
}

// ---------------------------------------------------------------- kernels ---
__global__ __launch_bounds__(1024) void k_zero(u32* bin_cnt, u32* surv_cnt) {
  int t = threadIdx.x;
  for (int j = t; j < NB * NCLS * CSTRIDE; j += 1024) bin_cnt[j] = 0u;
  if (t < NB) surv_cnt[t] = 0u;
}

// Single front-end pass: softmax only (no decode). One wave per row; block
// covers 125 rows of one image. Candidates aggregated in LDS class bins,
// flushed with ONE global atomic per non-empty class per block.
__global__ __launch_bounds__(1024) void k_score(const float* __restrict__ logits,
    u32* bin_cnt, u64* bins) {
  __shared__ u64 s_key[NCLS][LBIN];
  __shared__ u32 s_cnt[NCLS];
  int tid = threadIdx.x;
  int b = blockIdx.x / CHUNKS;
  int chunk = blockIdx.x % CHUNKS;
  int wave = tid >> 6, lane = tid & 63;
  if (tid < NCLS) s_cnt[tid] = 0u;
  __syncthreads();

  for (int rloc = wave; rloc < RPB; rloc += 16) {
    int rl = chunk * RPB + rloc;
    int r = b * NPER + rl;
    const float* lrow = logits + (size_t)r * NC;
    float xA = lrow[lane];
    float xB = (lane < NC - 64) ? lrow[64 + lane] : -3.0e38f;
    float mx = fmaxf(xA, xB);
    for (int o = 32; o; o >>= 1) mx = fmaxf(mx, __shfl_xor(mx, o));
    float eA = expf(xA - mx);
    float eB = (lane < NC - 64) ? expf(xB - mx) : 0.0f;
    float sm = eA + eB;
    for (int o = 32; o; o >>= 1) sm += __shfl_xor(sm, o);
    float sA = eA / sm;
    float sB = eB / sm;
    if (lane >= 1 && sA > 0.05f) {          // class = lane
      int ci = lane - 1;
      u32 orig = (u32)(rl * NCLS + ci);
      u64 key = ((u64)__float_as_uint(sA) << 22) | (u64)(0x3FFFFFu - orig);
      u32 lp = atomicAdd(&s_cnt[ci], 1u);
      if (lp < LBIN) s_key[ci][lp] = key;
      else {  // rare overflow: direct global (slot disjointness via same counter)
        u32 gp = atomicAdd(&bin_cnt[(b * NCLS + ci) * CSTRIDE], 1u);
        if (gp < BINCAP) bins[((size_t)b * NCLS + ci) * BINCAP + gp] = key;
      }
    }
    if (lane < NC - 64 && sB > 0.05f) {     // class = 64 + lane
      int ci = 63 + lane;
      u32 orig = (u32)(rl * NCLS + ci);
      u64 key = ((u64)__float_as_uint(sB) << 22) | (u64)(0x3FFFFFu - orig);
      u32 lp = atomicAdd(&s_cnt[ci], 1u);
      if (lp < LBIN) s_key[ci][lp] = key;
      else {
        u32 gp = atomicAdd(&bin_cnt[(b * NCLS + ci) * CSTRIDE], 1u);
        if (gp < BINCAP) bins[((size_t)b * NCLS + ci) * BINCAP + gp] = key;
      }
    }
  }
  __syncthreads();
  if (tid < NCLS) {
    u32 cnt = s_cnt[tid];
    u32 cl = (cnt < LBIN) ? cnt : LBIN;
    if (cl) {
      u32 base = atomicAdd(&bin_cnt[(b * NCLS + tid) * CSTRIDE], cl);
      u64* dst = bins + ((size_t)b * NCLS + tid) * BINCAP;
      for (u32 j = 0; j < cl; ++j) {
        u32 p = base + j;
        if (p < BINCAP) dst[p] = s_key[tid][j];
      }
    }
  }
}

// Per-(image,class) greedy NMS: ONE WAVE per (b,c). Bitonic sort of bin keys
// (desc), lazy box decode per 64-chunk, ballot-based greedy. Candidates
// failing MIN_SIZE are carried dead (never selected, never suppress) ==
// reference's pre-filter. Early exit at NDET survivors.
__global__ __launch_bounds__(64) void k_nms_class(const u32* __restrict__ bin_cnt,
    const u64* __restrict__ bins, const float* __restrict__ boxreg,
    const float* __restrict__ props, u32* surv_cnt, u64* skey, float4* sbox,
    const int* __restrict__ dh, const int* __restrict__ dw) {
  __shared__ u64 k[BINCAP];
  __shared__ float4 s_sb[NDET];   // offset boxes (IoU space)
  __shared__ float s_sa[NDET];
  __shared__ float4 s_raw[NDET];  // raw boxes (output space)
  __shared__ u64 s_sk[NDET];

  int b = blockIdx.x / NCLS;
  int ci = blockIdx.x % NCLS;
  u32 cnt = bin_cnt[(b * NCLS + ci) * CSTRIDE];
  int n = (int)((cnt < BINCAP) ? cnt : BINCAP);
  if (n <= 0) return;

  int lane = threadIdx.x;
  float H = (float)dh[0], W = (float)dw[0];
  float loff = (fmaxf(H, W) + 1.0f) * (float)(ci + 1);
  const u64* bin = bins + ((size_t)b * NCLS + ci) * BINCAP;
  const float4* props4 = (const float4*)props;
  const float4* breg4 = (const float4*)boxreg;

  int m = 1;
  while (m < n) m <<= 1;
  if (m < 2) m = 2;
  for (int j = lane; j < m; j += 64) k[j] = (j < n) ? bin[j] : 0ull;
  __syncthreads();
  for (int len = 2; len <= m; len <<= 1) {
    for (int str = len >> 1; str; str >>= 1) {
      for (int i = lane; i < (m >> 1); i += 64) {
        int a = 2 * str * (i / str) + (i % str);
        int c = a + str;
        bool desc = ((a & len) == 0);
        u64 ka = k[a], kc = k[c];
        if (desc ? (ka < kc) : (ka > kc)) { k[a] = kc; k[c] = ka; }
      }
      __syncthreads();  // single wave: no real barrier
    }
  }

  int S = 0;
  for (int base = 0; base < n && S < NDET; base += 64) {
    int i = base + lane;
    bool have = (i < n);
    u64 mykey = have ? k[i] : 0ull;
    float4 raw = make_float4(0.f, 0.f, 0.f, 0.f);
    float4 Bb = raw;
    float aB = 0.f;
    bool alive = false;
    if (have) {
      u32 orig = 0x3FFFFFu - (u32)(mykey & 0x3FFFFFu);
      u32 rl = orig / NCLS;
      int r = b * NPER + (int)rl;
      float4 p = props4[r];
      float w = p.z - p.x, h = p.w - p.y;
      float cx = p.x + 0.5f * w, cy = p.y + 0.5f * h;
      float4 rel = breg4[(size_t)r * NC + (ci + 1)];
      raw = decode_clip(rel, w, h, cx, cy, W, H);
      alive = ((raw.z - raw.x) >= 0.01f) && ((raw.w - raw.y) >= 0.01f);
      Bb = make_float4(raw.x + loff, raw.y + loff, raw.z + loff, raw.w + loff);
      aB = (Bb.z - Bb.x) * (Bb.w - Bb.y);
    }
    // suppression by survivors from earlier chunks
    for (int s = 0; s < S; ++s) {
      float4 A = s_sb[s];
      float aA = s_sa[s];
      float ix1 = fmaxf(A.x, Bb.x), iy1 = fmaxf(A.y, Bb.y);
      float ix2 = fminf(A.z, Bb.z), iy2 = fminf(A.w, Bb.w);
      float inter = fmaxf(ix2 - ix1, 0.0f) * fmaxf(iy2 - iy1, 0.0f);
      float iou = inter / fmaxf(aA + aB - inter, 1e-9f);
      if (alive && iou > 0.5f) alive = false;
    }
    u64 mask = __ballot(alive);
    while (mask && S < NDET) {
      int j = __builtin_ctzll(mask);
      float Ax = __shfl(Bb.x, j), Ay = __shfl(Bb.y, j);
      float Az = __shfl(Bb.z, j), Aw = __shfl(Bb.w, j);
      float aA = __shfl(aB, j);
      if (lane == j) {
        s_sb[S] = Bb; s_sa[S] = aB; s_raw[S] = raw; s_sk[S] = mykey;
      }
      float ix1 = fmaxf(Ax, Bb.x), iy1 = fmaxf(Ay, Bb.y);
      float ix2 = fminf(Az, Bb.z), iy2 = fminf(Aw, Bb.w);
      float inter = fmaxf(ix2 - ix1, 0.0f) * fmaxf(iy2 - iy1, 0.0f);
      float iou = inter / fmaxf(aA + aB - inter, 1e-9f);
      if (alive && iou > 0.5f) alive = false;  // selected lane leaves via IoU=1
      ++S;
      mask = __ballot(alive);
    }
    __syncthreads();
  }
  if (S == 0) return;
  int basep = 0;
  if (lane == 0) basep = (int)atomicAdd(surv_cnt + b, (u32)S);
  basep = __shfl(basep, 0);
  for (int i2 = lane; i2 < S; i2 += 64) {
    u32 p = (u32)(basep + i2);
    if (p < SURVCAP) {
      skey[(size_t)b * SURVCAP + p] = s_sk[i2];
      sbox[(size_t)b * SURVCAP + p] = s_raw[i2];
    }
  }
}

// Per-image exact top-NDET. Threshold T (100th-largest score bits) found by
// contention-free 32-step bisection (count via register compares + shfl
// reduce; NO LDS atomics -- score bit patterns cluster in exponent bytes and
// serialized a histogram approach). Compact >T plus ==T ties, bitonic sort
// by full 54-bit key = exact reference selection order.
__global__ __launch_bounds__(256) void k_top(const u32* __restrict__ surv_cnt,
    const u64* __restrict__ skey, const float4* __restrict__ sbox, float* out) {
  __shared__ u32 ssc[SURVCAP];
  __shared__ u32 s_red[4];
  __shared__ u32 s_cnt[2];
  __shared__ u64 fk[FKCAP];
  __shared__ u32 fs[FKCAP];

  int b = blockIdx.x;
  int tid = threadIdx.x;
  u32 ns = surv_cnt[b];
  if (ns > SURVCAP) ns = SURVCAP;
  const u64* kb = skey + (size_t)b * SURVCAP;

  for (u32 j = tid; j < ns; j += 256) ssc[j] = (u32)(kb[j] >> 22);
  if (tid == 0) { s_cnt[0] = 0; s_cnt[1] = 0; }
  __syncthreads();

  u32 T = 0;
  if (ns > NDET) {
    // find minimal x with count(s > x) < NDET  ==  100th-largest score value
    u32 lo = 0, hi = 0xFFFFFFFFu;
    while (lo < hi) {
      u32 mid = lo + ((hi - lo) >> 1);
      u32 c = 0;
      for (u32 j = tid; j < ns; j += 256) c += (ssc[j] > mid) ? 1u : 0u;
      for (int o = 32; o; o >>= 1) c += __shfl_xor(c, o);
      if ((tid & 63) == 0) s_red[tid >> 6] = c;
      __syncthreads();
      u32 totc = s_red[0] + s_red[1] + s_red[2] + s_red[3];
      __syncthreads();
      if (totc < NDET) hi = mid; else lo = mid + 1;
    }
    T = lo;
  }
  __syncthreads();

  for (u32 j = tid; j < ns; j += 256) {
    bool take = (ns <= NDET) || (ssc[j] > T);
    if (take) {
      u32 p = atomicAdd(&s_cnt[0], 1u);
      if (p < FKCAP) { fk[p] = kb[j]; fs[p] = j; }
    }
  }
  __syncthreads();
  if (tid == 0) s_cnt[1] = s_cnt[0];
  __syncthreads();
  if (ns > NDET) {  // append ==T ties; order fixed by full-key sort below
    for (u32 j = tid; j < ns; j += 256) {
      if (ssc[j] == T) {
        u32 p = atomicAdd(&s_cnt[1], 1u);
        if (p < FKCAP) { fk[p] = kb[j]; fs[p] = j; }
      }
    }
  }
  __syncthreads();
  u32 tot = s_cnt[1];
  if (tot > FKCAP) tot = FKCAP;
  u32 m2 = 1;
  while (m2 < tot) m2 <<= 1;
  if (m2 < 2) m2 = 2;
  for (u32 j = tot + tid; j < m2; j += 256) { fk[j] = 0ull; fs[j] = 0u; }
  __syncthreads();
  for (u32 len = 2; len <= m2; len <<= 1) {
    for (u32 str = len >> 1; str; str >>= 1) {
      for (u32 i = tid; i < (m2 >> 1); i += 256) {
        u32 a = 2 * str * (i / str) + (i % str);
        u32 c = a + str;
        bool desc = ((a & len) == 0);
        u64 ka = fk[a], kc = fk[c];
        if (desc ? (ka < kc) : (ka > kc)) {
          fk[a] = kc; fk[c] = ka;
          u32 t2 = fs[a]; fs[a] = fs[c]; fs[c] = t2;
        }
      }
      __syncthreads();
    }
  }
  // boxes[3200] | scores[800] | labels[800] | keep[800]
  if (tid < NDET) {
    u64 key = ((u32)tid < tot) ? fk[tid] : 0ull;
    float b0 = 0.f, b1 = 0.f, b2 = 0.f, b3 = 0.f, sc = 0.f, lb = 0.f, kp = 0.f;
    if (key) {
      float4 bx = sbox[(size_t)b * SURVCAP + fs[tid]];
      b0 = bx.x; b1 = bx.y; b2 = bx.z; b3 = bx.w;
      sc = __uint_as_float((u32)(key >> 22));
      u32 orig = 0x3FFFFFu - (u32)(key & 0x3FFFFFu);
      lb = (float)(orig % NCLS + 1u);
      kp = 1.0f;
    }
    float* ob = out + ((size_t)b * NDET + tid) * 4;
    ob[0] = b0; ob[1] = b1; ob[2] = b2; ob[3] = b3;
    out[NB * NDET * 4 + b * NDET + tid] = sc;
    out[NB * NDET * 5 + b * NDET + tid] = lb;
    out[NB * NDET * 6 + b * NDET + tid] = kp;
  }
}

// ---------------------------------------------------------------- launch ----
extern "C" void kernel_launch(void* const* d_in, const int* in_sizes, int n_in,
                              void* d_out, int out_size, void* d_ws, size_t ws_size,
                              hipStream_t stream) {
  const float* logits = (const float*)d_in[0];
  const float* boxreg = (const float*)d_in[1];
  const float* props  = (const float*)d_in[2];
  const int* dh = (const int*)d_in[3];
  const int* dw = (const int*)d_in[4];
  float* out = (float*)d_out;

  char* ws = (char*)d_ws;
  u32* bin_cnt  = (u32*)ws;                                   // 720*16 u32 = 45 KiB
  u32* surv_cnt = (u32*)(ws + 46080);                         // 8 u32
  u64* bins     = (u64*)(ws + 46336);                         // 720*512*8 = 2.95 MB
  char* p2 = ws + 46336 + (size_t)NB * NCLS * BINCAP * 8;
  u64* skey = (u64*)p2;                                       // 8*9216*8 = 590 KB
  float4* sbox = (float4*)(p2 + (size_t)NB * SURVCAP * 8);    // 8*9216*16 = 1.18 MB
  (void)ws_size;

  k_zero<<<1, 1024, 0, stream>>>(bin_cnt, surv_cnt);
  k_score<<<NB * CHUNKS, 1024, 0, stream>>>(logits, bin_cnt, bins);
  k_nms_class<<<NB * NCLS, 64, 0, stream>>>(bin_cnt, bins, boxreg, props,
                                            surv_cnt, skey, sbox, dh, dw);
  k_top<<<NB, 256, 0, stream>>>(surv_cnt, skey, sbox, out);
}